// Round 3
// baseline (290.084 us; speedup 1.0000x reference)
//
#include <hip/hip_runtime.h>
#include <math.h>

// TopKRouter: x[16384,2048] fp32, W[64,2048] fp32
// out: [0..32767] top2 indices (as float), [32768..65535] gates, [65536] aux
#define NTOK 16384
#define DDIM 2048
#define NEXP 64
#define BM   64               // tokens per block
#define NBLK (NTOK / BM)      // 256 blocks, 1 per CU
#define KPW  (DDIM / 8)       // 256 k per wave (k-split across 8 waves)
#define BKCH 16               // k per staging chunk
#define NCH  (KPW / BKCH)     // 16 chunks
#define ST   20               // LDS row stride (16 k + 4 pad): 20*4B, 16B-aligned,
                              // 20*tok mod 32 = 4*(5*tok mod 8) -> 8 distinct 4-bank
                              // groups covering all 32 banks => conflict-free b128

__global__ __launch_bounds__(512, 2) void router_kernel(
    const float* __restrict__ x, const float* __restrict__ W,
    float* __restrict__ part, float* __restrict__ out)
{
    __shared__ float smem[20480];   // loop: xs 8*1280 | ws 8*1280 (80 KB)
                                    // epilogue: red[4][64][65] = 16900 floats
    __shared__ float cnt[NEXP];

    const int tid  = threadIdx.x;
    const int lane = tid & 63;
    const int wv   = __builtin_amdgcn_readfirstlane(tid >> 6);  // 0..7 uniform
    const int m0   = blockIdx.x * BM;

    if (tid < NEXP) cnt[tid] = 0.0f;

    float* xsw = smem + wv * (BM * ST);            // wave-private x tile
    float* wsw = smem + 8 * (BM * ST) + wv * (BM * ST);

    const int tl = lane >> 3;       // token-group base: tokens tl + 8*i
    const int el = lane & 7;        // expert-group base: experts el + 8*j

    // staging lane mapping: 4 instrs, each covers 16 rows x 16 k
    const int qr = lane >> 2;          // 0..15 row within 16-row group
    const int c4 = (lane & 3) * 4;     // k offset 0,4,8,12

    const int kb0 = wv * KPW;

    float acc[8][8];
    #pragma unroll
    for (int i = 0; i < 8; ++i)
        #pragma unroll
        for (int j = 0; j < 8; ++j) acc[i][j] = 0.0f;

    float4 xg[4], wg[4];
    #pragma unroll
    for (int i = 0; i < 4; ++i) {
        xg[i] = *(const float4*)&x[(size_t)(m0 + qr + 16 * i) * DDIM + kb0 + c4];
        wg[i] = *(const float4*)&W[(size_t)(qr + 16 * i) * DDIM + kb0 + c4];
    }

    for (int ch = 0; ch < NCH; ++ch) {
        // staged regs -> wave-private LDS (in-order DS pipe: no barrier needed)
        #pragma unroll
        for (int i = 0; i < 4; ++i) {
            *(float4*)&xsw[(qr + 16 * i) * ST + c4] = xg[i];
            *(float4*)&wsw[(qr + 16 * i) * ST + c4] = wg[i];
        }
        // prefetch next chunk (overlaps compute below)
        if (ch < NCH - 1) {
            const int kb = kb0 + (ch + 1) * BKCH;
            #pragma unroll
            for (int i = 0; i < 4; ++i) {
                xg[i] = *(const float4*)&x[(size_t)(m0 + qr + 16 * i) * DDIM + kb + c4];
                wg[i] = *(const float4*)&W[(size_t)(qr + 16 * i) * DDIM + kb + c4];
            }
        }
        // compute 16 k: 4 quads of (16 b128 reads + 256 fmac)
        #pragma unroll
        for (int kq = 0; kq < 4; ++kq) {
            float4 xf[8], wf[8];
            #pragma unroll
            for (int i = 0; i < 8; ++i)
                xf[i] = *(const float4*)&xsw[(tl + 8 * i) * ST + kq * 4];
            #pragma unroll
            for (int j = 0; j < 8; ++j)
                wf[j] = *(const float4*)&wsw[(el + 8 * j) * ST + kq * 4];
            #pragma unroll
            for (int i = 0; i < 8; ++i)
                #pragma unroll
                for (int j = 0; j < 8; ++j) {
                    acc[i][j] = fmaf(xf[i].x, wf[j].x, acc[i][j]);
                    acc[i][j] = fmaf(xf[i].y, wf[j].y, acc[i][j]);
                    acc[i][j] = fmaf(xf[i].z, wf[j].z, acc[i][j]);
                    acc[i][j] = fmaf(xf[i].w, wf[j].w, acc[i][j]);
                }
        }
    }

    // ---- cross-wave reduction of partial logits: red[p][t][e], stride 65 ----
    __syncthreads();
    if (wv < 4) {   // phase A: waves 0-3 write their tiles
        #pragma unroll
        for (int i = 0; i < 8; ++i)
            #pragma unroll
            for (int j = 0; j < 8; ++j)
                smem[((wv * 64) + tl + 8 * i) * 65 + el + 8 * j] = acc[i][j];
    }
    __syncthreads();
    if (wv >= 4) {  // phase B: waves 4-7 accumulate into tile wv-4
        #pragma unroll
        for (int i = 0; i < 8; ++i)
            #pragma unroll
            for (int j = 0; j < 8; ++j) {
                int idx = (((wv - 4) * 64) + tl + 8 * i) * 65 + el + 8 * j;
                smem[idx] += acc[i][j];
            }
    }
    __syncthreads();
    {               // phase C: red0 += red2 (tid<128), red1 += red3 (tid 128..255)
        if (tid < 256) {
            int p  = tid >> 7;          // 0 or 1
            int sub = tid & 127;
            int e  = sub & 63, th = sub >> 6;
            #pragma unroll 8
            for (int tt = 0; tt < 32; ++tt) {
                int t = th * 32 + tt;
                smem[((p * 64) + t) * 65 + e] += smem[(((p + 2) * 64) + t) * 65 + e];
            }
        }
    }
    __syncthreads();
    {               // phase D: red0 += red1
        if (tid < 128) {
            int e = tid & 63, th = tid >> 6;
            #pragma unroll 8
            for (int tt = 0; tt < 32; ++tt) {
                int t = th * 32 + tt;
                smem[t * 65 + e] += smem[(64 + t) * 65 + e];
            }
        }
    }
    __syncthreads();

    // ---- softmax + top-2 epilogue: 8 threads per token ----
    const int m = tid >> 3;
    const int j = tid & 7;
    float l[8];
    #pragma unroll
    for (int i = 0; i < 8; ++i) l[i] = smem[m * 65 + j * 8 + i];

    float mx = l[0];
    #pragma unroll
    for (int i = 1; i < 8; ++i) mx = fmaxf(mx, l[i]);
    #pragma unroll
    for (int off = 1; off < 8; off <<= 1) mx = fmaxf(mx, __shfl_xor(mx, off, 8));

    float ev[8];
    float zs = 0.f;
    float v1 = -INFINITY, v2 = -INFINITY;
    int i1 = 0, i2 = 0;
    #pragma unroll
    for (int i = 0; i < 8; ++i) {
        ev[i] = __expf(l[i] - mx);
        zs += ev[i];
        int e = j * 8 + i;
        if (l[i] > v1)      { v2 = v1; i2 = i1; v1 = l[i]; i1 = e; }
        else if (l[i] > v2) { v2 = l[i]; i2 = e; }
    }
    #pragma unroll
    for (int off = 1; off < 8; off <<= 1) zs += __shfl_xor(zs, off, 8);

    // merge top-2 across 8 lanes (value desc, index asc on ties = lax.top_k)
    #pragma unroll
    for (int off = 1; off < 8; off <<= 1) {
        float ov1 = __shfl_xor(v1, off, 8);
        int   oi1 = __shfl_xor(i1, off, 8);
        float ov2 = __shfl_xor(v2, off, 8);
        int   oi2 = __shfl_xor(i2, off, 8);
        bool afirst = (v1 > ov1) || (v1 == ov1 && i1 < oi1);
        if (afirst) {
            bool t = (v2 > ov1) || (v2 == ov1 && i2 < oi1);
            v2 = t ? v2 : ov1;
            i2 = t ? i2 : oi1;
        } else {
            bool t = (ov2 > v1) || (ov2 == v1 && oi2 < i1);
            v2 = t ? ov2 : v1;
            i2 = t ? oi2 : i1;
            v1 = ov1;
            i1 = oi1;
        }
    }

    const float invz = 1.0f / zs;
    if (j == 0) {
        float p1 = invz;                      // v1 == mx exactly
        float p2 = __expf(v2 - mx) * invz;
        float sden = p1 + p2 + 1e-9f;
        int tok = m0 + m;
        out[tok * 2 + 0] = (float)i1;
        out[tok * 2 + 1] = (float)i2;
        out[32768 + tok * 2 + 0] = p1 / sden;
        out[32768 + tok * 2 + 1] = p2 / sden;
        atomicAdd(&cnt[i1], 1.0f);
        atomicAdd(&cnt[i2], 1.0f);
    }

    // probs writeback (own slots only)
    #pragma unroll
    for (int i = 0; i < 8; ++i) smem[m * 65 + j * 8 + i] = ev[i] * invz;
    __syncthreads();

    // per-block partials (no global atomics, no zero-init needed)
    if (tid < NEXP) {
        part[(size_t)blockIdx.x * 128 + tid] = cnt[tid];
    } else if (tid < 128) {
        int e = tid - 64;
        float s = 0.f;
        #pragma unroll 8
        for (int t = 0; t < BM; ++t) s += smem[t * 65 + e];
        part[(size_t)blockIdx.x * 128 + tid] = s;
    }
}

__global__ void finalize_kernel(const float* __restrict__ part,
                                float* __restrict__ out)
{
    __shared__ float buf[256];
    const int t = threadIdx.x;          // 256 threads
    const int e = t & 127, h = t >> 7;  // each half sums 128 blocks, 4-unrolled
    float s0 = 0.f, s1 = 0.f, s2 = 0.f, s3 = 0.f;
    for (int b = h * 128; b < h * 128 + 128; b += 4) {
        s0 += part[(size_t)(b + 0) * 128 + e];
        s1 += part[(size_t)(b + 1) * 128 + e];
        s2 += part[(size_t)(b + 2) * 128 + e];
        s3 += part[(size_t)(b + 3) * 128 + e];
    }
    buf[t] = (s0 + s1) + (s2 + s3);
    __syncthreads();
    if (t < 64) {
        float c = buf[t] + buf[t + 128];            // counts[e]
        float p = buf[t + 64] + buf[t + 192];       // probsum[e]
        float term = (c / (float)(NTOK * 2)) * (p / (float)NTOK);
        #pragma unroll
        for (int off = 1; off < 64; off <<= 1) term += __shfl_xor(term, off, 64);
        if (t == 0) out[65536] = 0.01f * (float)NEXP * term;
    }
}

extern "C" void kernel_launch(void* const* d_in, const int* in_sizes, int n_in,
                              void* d_out, int out_size, void* d_ws, size_t ws_size,
                              hipStream_t stream) {
    const float* x = (const float*)d_in[0];   // [4,4096,2048]
    const float* W = (const float*)d_in[1];   // [64,2048]
    float* out  = (float*)d_out;              // 65537 floats
    float* part = (float*)d_ws;               // 256*128 floats = 128 KB

    router_kernel<<<NBLK, 512, 0, stream>>>(x, W, part, out);
    finalize_kernel<<<1, 256, 0, stream>>>(part, out);
}

// Round 4
// 289.716 us; speedup vs baseline: 1.0013x; 1.0013x over previous
//
#include <hip/hip_runtime.h>
#include <math.h>

// TopKRouter: x[16384,2048] fp32, W[64,2048] fp32
// out: [0..32767] top2 indices (as float), [32768..65535] gates, [65536] aux
#define NTOK 16384
#define DDIM 2048
#define NEXP 64
#define BM   64               // tokens per block
#define NBLK (NTOK / BM)      // 256 blocks, 1 per CU
#define KPW  (DDIM / 8)       // 256 k per wave (k-split across 8 waves)
#define NCH  16               // chunks of 16 k per wave
#define XST  20               // xs row stride: tl*20 mod 32 covers 8 distinct
                              // 4-bank groups -> conflict-free b128 broadcast reads
#define RS   66               // reduction stride (even for float2, 2t+e banking)

__global__ __launch_bounds__(512) void router_kernel(
    const float* __restrict__ x, const float* __restrict__ W,
    float* __restrict__ part, float* __restrict__ out)
{
    __shared__ float xs[8][BM * XST];   // 8 waves x 64 tok x 20 = 40 KB (wave-private)
    __shared__ float red[4 * BM * RS];  // 67.6 KB cross-wave reduction
    __shared__ float cnt[NEXP];

    const int tid  = threadIdx.x;
    const int lane = tid & 63;
    const int wv   = __builtin_amdgcn_readfirstlane(tid >> 6);  // 0..7 uniform
    const int m0   = blockIdx.x * BM;

    if (tid < NEXP) cnt[tid] = 0.0f;

    const int tl = lane >> 3;      // thread tokens: tl + 8*i
    const int el = lane & 7;       // thread experts: el*8 + j (contiguous rows)
    const int qr = lane >> 2;      // staging row within 16-row group
    const int c4 = (lane & 3) * 4; // staging k offset
    const int kb0 = wv * KPW;

    float* xw = xs[wv];

    float acc[8][8];
    #pragma unroll
    for (int i = 0; i < 8; ++i)
        #pragma unroll
        for (int j = 0; j < 8; ++j) acc[i][j] = 0.0f;

    const float* xstg = x + (size_t)(m0 + qr) * DDIM + kb0 + c4;
    const float* wrow = W + (size_t)(el * 8) * DDIM + kb0;

    // prefetch x chunk 0 (coalesced) and W kq 0 (direct-global, L2-hot)
    float4 stg[4];
    #pragma unroll
    for (int s = 0; s < 4; ++s)
        stg[s] = *(const float4*)(xstg + (size_t)s * 16 * DDIM);

    float4 wfa[8], wfb[8];
    #pragma unroll
    for (int j = 0; j < 8; ++j)
        wfa[j] = *(const float4*)(wrow + (size_t)j * DDIM);

    for (int ch = 0; ch < NCH; ++ch) {
        // staged regs -> wave-private LDS (in-order DS pipe: no barrier, no dbuf)
        #pragma unroll
        for (int s = 0; s < 4; ++s)
            *(float4*)&xw[(qr + 16 * s) * XST + c4] = stg[s];
        // prefetch next x chunk (last iter reloads chunk 0: harmless)
        {
            const int chn = (ch + 1 < NCH) ? ch + 1 : 0;
            #pragma unroll
            for (int s = 0; s < 4; ++s)
                stg[s] = *(const float4*)(xstg + (size_t)s * 16 * DDIM + chn * 16);
        }
        // 4 kq of 4k each; W 1-deep double-buffered (vmcnt-pipelined)
        #pragma unroll
        for (int kq = 0; kq < 4; ++kq) {
            const int kk = ch * 4 + kq;
            float4* cur = (kq & 1) ? wfb : wfa;
            float4* nxt = (kq & 1) ? wfa : wfb;
            const int kkn = (kk + 1 < 4 * NCH) ? kk + 1 : 0;
            #pragma unroll
            for (int j = 0; j < 8; ++j)
                nxt[j] = *(const float4*)(wrow + (size_t)j * DDIM + kkn * 4);
            float4 xf[8];
            #pragma unroll
            for (int i = 0; i < 8; ++i)
                xf[i] = *(const float4*)&xw[(tl + 8 * i) * XST + kq * 4];
            #pragma unroll
            for (int i = 0; i < 8; ++i)
                #pragma unroll
                for (int j = 0; j < 8; ++j) {
                    acc[i][j] = fmaf(xf[i].x, cur[j].x, acc[i][j]);
                    acc[i][j] = fmaf(xf[i].y, cur[j].y, acc[i][j]);
                    acc[i][j] = fmaf(xf[i].z, cur[j].z, acc[i][j]);
                    acc[i][j] = fmaf(xf[i].w, cur[j].w, acc[i][j]);
                }
        }
    }

    // ---- cross-wave reduction: red[p][t][e], stride RS=66, float2 ops ----
    __syncthreads();
    if (wv < 4) {   // phase A: waves 0-3 write tiles (2tl+8el banks -> 2-way, free)
        #pragma unroll
        for (int i = 0; i < 8; ++i)
            #pragma unroll
            for (int q = 0; q < 4; ++q)
                *(float2*)&red[(wv * BM + tl + 8 * i) * RS + el * 8 + 2 * q] =
                    make_float2(acc[i][2 * q], acc[i][2 * q + 1]);
    }
    __syncthreads();
    if (wv >= 4) {  // phase B: waves 4-7 accumulate into tile wv-4
        #pragma unroll
        for (int i = 0; i < 8; ++i)
            #pragma unroll
            for (int q = 0; q < 4; ++q) {
                float2* p = (float2*)&red[((wv - 4) * BM + tl + 8 * i) * RS + el * 8 + 2 * q];
                float2 r = *p;
                r.x += acc[i][2 * q];
                r.y += acc[i][2 * q + 1];
                *p = r;
            }
    }
    __syncthreads();
    {   // phase C: tile0 += tile2, tile1 += tile3 (all 512 threads)
        const int f = tid >> 8, v = tid & 255;
        const int tok = v >> 2, qb = (v & 3) * 8;
        #pragma unroll
        for (int t = 0; t < 8; ++t) {
            int eo = (qb + t) * 2;
            float2* d = (float2*)&red[(f * BM + tok) * RS + eo];
            float2  s = *(float2*)&red[((f + 2) * BM + tok) * RS + eo];
            float2  a = *d;
            a.x += s.x; a.y += s.y;
            *d = a;
        }
    }
    __syncthreads();
    {   // phase D: tile0 += tile1
        const int tok = tid >> 3, qb = (tid & 7) * 4;
        #pragma unroll
        for (int t = 0; t < 4; ++t) {
            int eo = (qb + t) * 2;
            float2* d = (float2*)&red[tok * RS + eo];
            float2  s = *(float2*)&red[(BM + tok) * RS + eo];
            float2  a = *d;
            a.x += s.x; a.y += s.y;
            *d = a;
        }
    }
    __syncthreads();

    // ---- softmax + top-2: 8 threads per token ----
    const int m = tid >> 3;
    const int j = tid & 7;
    float l[8];
    #pragma unroll
    for (int i = 0; i < 8; ++i) l[i] = red[m * RS + j * 8 + i];

    float mx = l[0];
    #pragma unroll
    for (int i = 1; i < 8; ++i) mx = fmaxf(mx, l[i]);
    #pragma unroll
    for (int off = 1; off < 8; off <<= 1) mx = fmaxf(mx, __shfl_xor(mx, off, 8));

    float ev[8];
    float zs = 0.f;
    float v1 = -INFINITY, v2 = -INFINITY;
    int i1 = 0, i2 = 0;
    #pragma unroll
    for (int i = 0; i < 8; ++i) {
        ev[i] = __expf(l[i] - mx);
        zs += ev[i];
        int e = j * 8 + i;
        if (l[i] > v1)      { v2 = v1; i2 = i1; v1 = l[i]; i1 = e; }
        else if (l[i] > v2) { v2 = l[i]; i2 = e; }
    }
    #pragma unroll
    for (int off = 1; off < 8; off <<= 1) zs += __shfl_xor(zs, off, 8);

    // merge top-2 across 8 lanes (value desc, index asc on ties = lax.top_k)
    #pragma unroll
    for (int off = 1; off < 8; off <<= 1) {
        float ov1 = __shfl_xor(v1, off, 8);
        int   oi1 = __shfl_xor(i1, off, 8);
        float ov2 = __shfl_xor(v2, off, 8);
        int   oi2 = __shfl_xor(i2, off, 8);
        bool afirst = (v1 > ov1) || (v1 == ov1 && i1 < oi1);
        if (afirst) {
            bool t = (v2 > ov1) || (v2 == ov1 && i2 < oi1);
            v2 = t ? v2 : ov1;
            i2 = t ? i2 : oi1;
        } else {
            bool t = (ov2 > v1) || (ov2 == v1 && oi2 < i1);
            v2 = t ? ov2 : v1;
            i2 = t ? oi2 : i1;
            v1 = ov1;
            i1 = oi1;
        }
    }

    const float invz = 1.0f / zs;
    if (j == 0) {
        float p1 = invz;                      // v1 == mx exactly
        float p2 = __expf(v2 - mx) * invz;
        float sden = p1 + p2 + 1e-9f;
        int tok = m0 + m;
        out[tok * 2 + 0] = (float)i1;
        out[tok * 2 + 1] = (float)i2;
        out[32768 + tok * 2 + 0] = p1 / sden;
        out[32768 + tok * 2 + 1] = p2 / sden;
        atomicAdd(&cnt[i1], 1.0f);
        atomicAdd(&cnt[i2], 1.0f);
    }

    // probs writeback (own slots only)
    #pragma unroll
    for (int i = 0; i < 8; ++i) red[m * RS + j * 8 + i] = ev[i] * invz;
    __syncthreads();

    // per-block partials (no global atomics, no zero-init needed)
    if (tid < NEXP) {
        part[(size_t)blockIdx.x * 128 + tid] = cnt[tid];
    } else if (tid < 128) {
        int e = tid - 64;
        float s = 0.f;
        #pragma unroll 8
        for (int t = 0; t < BM; ++t) s += red[t * RS + e];
        part[(size_t)blockIdx.x * 128 + tid] = s;
    }
}

__global__ void finalize_kernel(const float* __restrict__ part,
                                float* __restrict__ out)
{
    __shared__ float buf[256];
    const int t = threadIdx.x;          // 256 threads
    const int e = t & 127, h = t >> 7;  // each half sums 128 blocks, 4-unrolled
    float s0 = 0.f, s1 = 0.f, s2 = 0.f, s3 = 0.f;
    for (int b = h * 128; b < h * 128 + 128; b += 4) {
        s0 += part[(size_t)(b + 0) * 128 + e];
        s1 += part[(size_t)(b + 1) * 128 + e];
        s2 += part[(size_t)(b + 2) * 128 + e];
        s3 += part[(size_t)(b + 3) * 128 + e];
    }
    buf[t] = (s0 + s1) + (s2 + s3);
    __syncthreads();
    if (t < 64) {
        float c = buf[t] + buf[t + 128];            // counts[e]
        float p = buf[t + 64] + buf[t + 192];       // probsum[e]
        float term = (c / (float)(NTOK * 2)) * (p / (float)NTOK);
        #pragma unroll
        for (int off = 1; off < 64; off <<= 1) term += __shfl_xor(term, off, 64);
        if (t == 0) out[65536] = 0.01f * (float)NEXP * term;
    }
}

extern "C" void kernel_launch(void* const* d_in, const int* in_sizes, int n_in,
                              void* d_out, int out_size, void* d_ws, size_t ws_size,
                              hipStream_t stream) {
    const float* x = (const float*)d_in[0];   // [4,4096,2048]
    const float* W = (const float*)d_in[1];   // [64,2048]
    float* out  = (float*)d_out;              // 65537 floats
    float* part = (float*)d_ws;               // 256*128 floats = 128 KB

    router_kernel<<<NBLK, 512, 0, stream>>>(x, W, part, out);
    finalize_kernel<<<1, 256, 0, stream>>>(part, out);
}

// Round 5
// 241.908 us; speedup vs baseline: 1.1991x; 1.1976x over previous
//
#include <hip/hip_runtime.h>
#include <math.h>

// TopKRouter: x[16384,2048] fp32, W[64,2048] fp32
// out: [0..32767] top2 indices (as float), [32768..65535] gates, [65536] aux
// Strategy: split-fp16 MFMA GEMM (x=xh+xl, W=wh+wl, 4 cross-products into fp32
// acc via v_mfma_f32_16x16x32_f16) -> error ~1e-7, same class as fp32 ref.
// ws layout: [0..127] float accg (counts|probsums); then Wh, Wl fp16 frag-linear.
#define NTOK 16384
#define DDIM 2048
#define NEXP 64
#define TM   32                 // tokens per block
#define NBLK (NTOK / TM)        // 512 blocks -> 2 blocks/CU
#define NCH  32                 // K chunks of 64
#define NS   64                 // K32 MFMA steps total

typedef _Float16 half4v __attribute__((ext_vector_type(4)));
typedef _Float16 half8v __attribute__((ext_vector_type(8)));
typedef float    f32x4  __attribute__((ext_vector_type(4)));

// W prep: fp32 -> (wh, wl) fp16 pair in MFMA-B fragment-linear layout:
// element (e,k): S=k>>5, nb=e>>4, nl=e&15, q=(k>>3)&3, j=k&7
// off = S*2048 + nb*512 + q*128 + nl*8 + j   (halfs)
__global__ __launch_bounds__(256) void prep_kernel(const float* __restrict__ W,
                                                   _Float16* __restrict__ Wh,
                                                   _Float16* __restrict__ Wl,
                                                   float* __restrict__ accg) {
    int idx = blockIdx.x * 256 + threadIdx.x;       // 512 blocks -> 131072
    int e = idx >> 11, k = idx & 2047;
    float w = W[idx];
    _Float16 h = (_Float16)w;
    _Float16 l = (_Float16)(w - (float)h);
    int S = k >> 5, nb = e >> 4, nl = e & 15, q = (k >> 3) & 3, j = k & 7;
    size_t off = (size_t)S * 2048 + nb * 512 + q * 128 + nl * 8 + j;
    Wh[off] = h;
    Wl[off] = l;
    if (blockIdx.x == 0 && threadIdx.x < 128) accg[threadIdx.x] = 0.0f;
}

__device__ inline void cvt_store(_Float16* __restrict__ Hp, _Float16* __restrict__ Lp,
                                 int off, float4 v) {
    half4v h, l;
    h.x = (_Float16)v.x; l.x = (_Float16)(v.x - (float)h.x);
    h.y = (_Float16)v.y; l.y = (_Float16)(v.y - (float)h.y);
    h.z = (_Float16)v.z; l.z = (_Float16)(v.z - (float)h.z);
    h.w = (_Float16)v.w; l.w = (_Float16)(v.w - (float)h.w);
    *(half4v*)&Hp[off] = h;
    *(half4v*)&Lp[off] = l;
}

#define MFMA16(a, b, c) __builtin_amdgcn_mfma_f32_16x16x32_f16((a), (b), (c), 0, 0, 0)

__global__ __launch_bounds__(256) void router_kernel(
    const float* __restrict__ x, const _Float16* __restrict__ Wh,
    const _Float16* __restrict__ Wl, float* __restrict__ accg,
    float* __restrict__ out)
{
    // A (x) fp16 frag-linear, double-buffered: region (mi*2+s) of 64 lanes x 8
    __shared__ __align__(16) _Float16 Ah[2][2048];   // 8 KB
    __shared__ __align__(16) _Float16 Al[2][2048];   // 8 KB
    __shared__ float lgt[TM][NEXP + 1];              // 8.3 KB
    __shared__ float cnt[NEXP];

    const int tid  = threadIdx.x;
    const int lane = tid & 63;
    const int wv   = __builtin_amdgcn_readfirstlane(tid >> 6);  // 0..3: expert block
    const int m0   = blockIdx.x * TM;

    if (tid < NEXP) cnt[tid] = 0.0f;

    // ---- staging map: thread t loads x[tok][kk..kk+3] for tok=t>>4(+16), kk=(t&15)*4
    const int tok0 = tid >> 4;
    const int kk0  = (tid & 15) * 4;
    const int s0   = kk0 >> 5, q0 = (kk0 >> 3) & 3, j00 = kk0 & 7;
    const int offA0 = (s0 * 64 + q0 * 16 + tok0) * 8 + j00;   // mi=0 region
    const int offA1 = offA0 + 1024;                            // mi=1 region

    const float* gx0 = x + (size_t)(m0 + tok0) * DDIM + kk0;
    const float* gx1 = gx0 + (size_t)16 * DDIM;

    // W-frag pointers for this wave's expert block (frag-linear, L2-hot)
    const _Float16* Whp = Wh + wv * 512 + lane * 8;
    const _Float16* Wlp = Wl + wv * 512 + lane * 8;

    f32x4 acc0 = {0.f, 0.f, 0.f, 0.f};
    f32x4 acc1 = {0.f, 0.f, 0.f, 0.f};

    // prologue: prefetch chunks 0,1 and W-frag step 0
    float4 stg[2][2];
    stg[0][0] = *(const float4*)(gx0);
    stg[0][1] = *(const float4*)(gx1);
    stg[1][0] = *(const float4*)(gx0 + 64);
    stg[1][1] = *(const float4*)(gx1 + 64);
    half8v whC = *(const half8v*)(Whp);
    half8v wlC = *(const half8v*)(Wlp);

    for (int ch = 0; ch < NCH; ++ch) {
        const int p = ch & 1;
        // stage chunk ch regs -> LDS (fp16 split, frag-linear)
        cvt_store(&Ah[p][0], &Al[p][0], offA0, stg[p][0]);
        cvt_store(&Ah[p][0], &Al[p][0], offA1, stg[p][1]);
        // depth-2 register prefetch (vmcnt stays in flight across barrier)
        const int cf = (ch + 2 < NCH) ? ch + 2 : 0;
        stg[p][0] = *(const float4*)(gx0 + cf * 64);
        stg[p][1] = *(const float4*)(gx1 + cf * 64);
        __syncthreads();   // single barrier per chunk: dbuf parity makes it safe
        #pragma unroll
        for (int s = 0; s < 2; ++s) {
            const int Sg  = ch * 2 + s;
            const int SgN = (Sg + 1) & (NS - 1);
            half8v whN = *(const half8v*)(Whp + (size_t)SgN * 2048);
            half8v wlN = *(const half8v*)(Wlp + (size_t)SgN * 2048);
            half8v a0h = *(const half8v*)&Ah[p][(s * 64 + lane) * 8];
            half8v a0l = *(const half8v*)&Al[p][(s * 64 + lane) * 8];
            half8v a1h = *(const half8v*)&Ah[p][((2 + s) * 64 + lane) * 8];
            half8v a1l = *(const half8v*)&Al[p][((2 + s) * 64 + lane) * 8];
            acc0 = MFMA16(a0l, wlC, acc0);
            acc0 = MFMA16(a0l, whC, acc0);
            acc0 = MFMA16(a0h, wlC, acc0);
            acc0 = MFMA16(a0h, whC, acc0);
            acc1 = MFMA16(a1l, wlC, acc1);
            acc1 = MFMA16(a1l, whC, acc1);
            acc1 = MFMA16(a1h, wlC, acc1);
            acc1 = MFMA16(a1h, whC, acc1);
            whC = whN;
            wlC = wlN;
        }
    }

    // ---- C layout: row m = (lane>>4)*4 + r, col n = lane&15 (m89-verified) ----
    {
        const int q  = lane >> 4;
        const int nl = lane & 15;
        #pragma unroll
        for (int r = 0; r < 4; ++r) {
            lgt[q * 4 + r][wv * 16 + nl]      = acc0[r];
            lgt[16 + q * 4 + r][wv * 16 + nl] = acc1[r];
        }
    }
    __syncthreads();

    // ---- softmax + top-2: 8 threads per token (32 tok x 8 = 256 thr) ----
    const int m = tid >> 3;
    const int j = tid & 7;
    float l[8];
    #pragma unroll
    for (int i = 0; i < 8; ++i) l[i] = lgt[m][j * 8 + i];

    float mx = l[0];
    #pragma unroll
    for (int i = 1; i < 8; ++i) mx = fmaxf(mx, l[i]);
    #pragma unroll
    for (int off = 1; off < 8; off <<= 1) mx = fmaxf(mx, __shfl_xor(mx, off, 8));

    float ev[8];
    float zs = 0.f;
    float v1 = -INFINITY, v2 = -INFINITY;
    int i1 = 0, i2 = 0;
    #pragma unroll
    for (int i = 0; i < 8; ++i) {
        ev[i] = __expf(l[i] - mx);
        zs += ev[i];
        int e = j * 8 + i;
        if (l[i] > v1)      { v2 = v1; i2 = i1; v1 = l[i]; i1 = e; }
        else if (l[i] > v2) { v2 = l[i]; i2 = e; }
    }
    #pragma unroll
    for (int off = 1; off < 8; off <<= 1) zs += __shfl_xor(zs, off, 8);

    // merge top-2 across 8 lanes (value desc, index asc on ties = lax.top_k)
    #pragma unroll
    for (int off = 1; off < 8; off <<= 1) {
        float ov1 = __shfl_xor(v1, off, 8);
        int   oi1 = __shfl_xor(i1, off, 8);
        float ov2 = __shfl_xor(v2, off, 8);
        int   oi2 = __shfl_xor(i2, off, 8);
        bool afirst = (v1 > ov1) || (v1 == ov1 && i1 < oi1);
        if (afirst) {
            bool t = (v2 > ov1) || (v2 == ov1 && i2 < oi1);
            v2 = t ? v2 : ov1;
            i2 = t ? i2 : oi1;
        } else {
            bool t = (ov2 > v1) || (ov2 == v1 && oi2 < i1);
            v2 = t ? ov2 : v1;
            i2 = t ? oi2 : i1;
            v1 = ov1;
            i1 = oi1;
        }
    }

    const float invz = 1.0f / zs;
    if (j == 0) {
        float p1 = invz;                      // v1 == mx exactly
        float p2 = __expf(v2 - mx) * invz;
        float sden = p1 + p2 + 1e-9f;
        int tok = m0 + m;
        out[tok * 2 + 0] = (float)i1;
        out[tok * 2 + 1] = (float)i2;
        out[32768 + tok * 2 + 0] = p1 / sden;
        out[32768 + tok * 2 + 1] = p2 / sden;
        atomicAdd(&cnt[i1], 1.0f);
        atomicAdd(&cnt[i2], 1.0f);
    }

    // probs writeback (own slots only)
    #pragma unroll
    for (int i = 0; i < 8; ++i) lgt[m][j * 8 + i] = ev[i] * invz;
    __syncthreads();

    // global accumulators (accg zeroed by prep each launch)
    if (tid < NEXP) {
        atomicAdd(&accg[tid], cnt[tid]);
    } else if (tid < 128) {
        int e = tid - 64;
        float s = 0.f;
        #pragma unroll 8
        for (int t = 0; t < TM; ++t) s += lgt[t][e];
        atomicAdd(&accg[64 + e], s);
    }
}

__global__ void finalize_kernel(const float* __restrict__ accg,
                                float* __restrict__ out)
{
    int t = threadIdx.x;   // 64 threads
    float c = accg[t];
    float p = accg[64 + t];
    float term = (c / (float)(NTOK * 2)) * (p / (float)NTOK);
    #pragma unroll
    for (int off = 1; off < 64; off <<= 1) term += __shfl_xor(term, off, 64);
    if (t == 0) out[65536] = 0.01f * (float)NEXP * term;
}

extern "C" void kernel_launch(void* const* d_in, const int* in_sizes, int n_in,
                              void* d_out, int out_size, void* d_ws, size_t ws_size,
                              hipStream_t stream) {
    const float* x = (const float*)d_in[0];   // [4,4096,2048]
    const float* W = (const float*)d_in[1];   // [64,2048]
    float* out  = (float*)d_out;              // 65537 floats
    float* accg = (float*)d_ws;               // 128 floats
    _Float16* Wh = (_Float16*)(accg + 128);   // 131072 halfs (256 KB)
    _Float16* Wl = Wh + (size_t)DDIM * NEXP;  // 131072 halfs (256 KB)

    prep_kernel<<<512, 256, 0, stream>>>(W, Wh, Wl, accg);
    router_kernel<<<NBLK, 256, 0, stream>>>(x, Wh, Wl, accg, out);
    finalize_kernel<<<1, 64, 0, stream>>>(accg, out);
}